// Round 1
// baseline (191.750 us; speedup 1.0000x reference)
//
#include <hip/hip_runtime.h>
#include <hip/hip_bf16.h>
#include <cstdint>
#include <cstddef>

// Problem constants (fixed by the reference)
#define NCAT   8
#define DIN    64
#define HID    1024
#define NBATCH 256
#define HSEQ   64
#define NTOK   (NBATCH * HSEQ)   // 16384

typedef __bf16 bf16x8 __attribute__((ext_vector_type(8)));
typedef __bf16 bf16x4 __attribute__((ext_vector_type(4)));
typedef float  f32x4  __attribute__((ext_vector_type(4)));

__device__ __forceinline__ void async16(const void* g, void* l) {
    __builtin_amdgcn_global_load_lds(
        (const __attribute__((address_space(1))) unsigned int*)g,
        (__attribute__((address_space(3))) unsigned int*)l,
        16, 0, 0);
}

// ---------------- prep kernels ----------------

// PE table: pe[t][2i] = sin(t*div_i), pe[t][2i+1] = cos(t*div_i)
__global__ void pe_kernel(float* __restrict__ pe) {
    const int t = blockIdx.x;        // 0..63
    const int i = threadIdx.x;       // 0..511
    const float div = expf((float)(2 * i) * (-9.210340371976184f / 1024.f));
    const float a = (float)t * div;
    pe[t * HID + 2 * i]     = sinf(a);
    pe[t * HID + 2 * i + 1] = cosf(a);
}

// f32 -> bf16 elementwise (x: [NTOK][64])
__global__ void cvt_x_kernel(const float* __restrict__ x, __bf16* __restrict__ xb) {
    const size_t i = (size_t)blockIdx.x * blockDim.x + threadIdx.x; // 0..262143
    const float4 v = ((const float4*)x)[i];
    bf16x4 o = { (__bf16)v.x, (__bf16)v.y, (__bf16)v.z, (__bf16)v.w };
    *(bf16x4*)(xb + 4 * i) = o;
}

// W [C][K][N] f32 -> Wt [C][N][K] bf16 (64x64 LDS-tiled transpose)
__global__ __launch_bounds__(256)
void transpose_kernel(const float* __restrict__ W, __bf16* __restrict__ Wt,
                      const int K, const int N) {
    __shared__ float tile[64][65];
    const int c = blockIdx.z;
    const float* Wc = W + (size_t)c * K * N;
    __bf16* Wtc = Wt + (size_t)c * N * K;
    const int k0 = blockIdx.y * 64, n0 = blockIdx.x * 64;
    const int t = threadIdx.x;
    const int cl = (t & 15) * 4, rw = t >> 4;
#pragma unroll
    for (int p = 0; p < 4; ++p) {
        const int r = rw + p * 16;
        const float4 v = *(const float4*)(Wc + (size_t)(k0 + r) * N + (n0 + cl));
        tile[r][cl]     = v.x;
        tile[r][cl + 1] = v.y;
        tile[r][cl + 2] = v.z;
        tile[r][cl + 3] = v.w;
    }
    __syncthreads();
    const int n = t >> 2, ks = (t & 3) * 16;
    bf16x8 o0, o1;
#pragma unroll
    for (int i = 0; i < 8; ++i) o0[i] = (__bf16)tile[ks + i][n];
#pragma unroll
    for (int i = 0; i < 8; ++i) o1[i] = (__bf16)tile[ks + 8 + i][n];
    __bf16* dst = Wtc + (size_t)(n0 + n) * K + (k0 + ks);
    *(bf16x8*)dst = o0;
    *(bf16x8*)(dst + 8) = o1;
}

// ---------------- category-gated GEMM ----------------
// A: [NTOK][K] bf16 row-major. Bt: [C][HID][K] bf16 (transposed weights).
// Block = one batch (64 rows, uniform category) x 256 output cols.
// EPI: 0 = +bias, relu, +pe -> bf16 ; 1 = +bias, relu -> bf16 ; 2 = +bias -> f32
template <int K, int EPI>
__global__ __launch_bounds__(256, 2)
void gemm_cat(const __bf16* __restrict__ A,
              const __bf16* __restrict__ Bt,
              const float* __restrict__ bias,
              const float* __restrict__ pe,
              const int* __restrict__ cat,
              __bf16* __restrict__ hout,
              float* __restrict__ fout) {
    __shared__ __bf16 Ab[2][64 * 64];    // 16 KB
    __shared__ __bf16 Bb[2][256 * 64];   // 64 KB
    const int tid = threadIdx.x;
    const int lane = tid & 63;
    const int wv = tid >> 6;             // 0..3
    const int batch = blockIdx.y;
    const int n0 = blockIdx.x * 256;
    const int cid = cat[batch];

    const __bf16* Agb = A + (size_t)batch * HSEQ * K;
    const __bf16* Bgb = Bt + ((size_t)cid * HID + n0) * K;

    const int srow = lane >> 3;           // 0..7
    const int scol = (lane & 7) * 16;     // byte within a 128B (64 bf16) row-slice

    auto stage = [&](int buf, int k0) {
        // A tile: 64 rows x 64 k (8 KB) -> 8 wave-issues (2 per wave)
#pragma unroll
        for (int j = 0; j < 2; ++j) {
            const int issue = wv * 2 + j;
            const int row = issue * 8 + srow;
            const char* src = (const char*)(Agb + (size_t)row * K + k0) + scol;
            char* dst = (char*)(&Ab[buf][0]) + issue * 1024;
            async16(src, dst);
        }
        // B tile: 256 rows x 64 k (32 KB) -> 32 wave-issues (8 per wave)
#pragma unroll
        for (int j = 0; j < 8; ++j) {
            const int issue = wv * 8 + j;
            const int row = issue * 8 + srow;
            const char* src = (const char*)(Bgb + (size_t)row * K + k0) + scol;
            char* dst = (char*)(&Bb[buf][0]) + issue * 1024;
            async16(src, dst);
        }
    };

    f32x4 acc[4][4] = {};
    stage(0, 0);
    const int lr = lane & 15, lh = lane >> 4;
    __syncthreads();  // drains vmcnt(0): buf0 ready

    int cur = 0;
    const int NT = K / 64;
    for (int t = 0; t < NT; ++t) {
        if (t + 1 < NT) stage(cur ^ 1, (t + 1) * 64);
#pragma unroll
        for (int kk = 0; kk < 2; ++kk) {
            bf16x8 af[4], bfr[4];
#pragma unroll
            for (int mi = 0; mi < 4; ++mi)
                af[mi] = *(const bf16x8*)&Ab[cur][(mi * 16 + lr) * 64 + kk * 32 + lh * 8];
#pragma unroll
            for (int ni = 0; ni < 4; ++ni)
                bfr[ni] = *(const bf16x8*)&Bb[cur][(wv * 64 + ni * 16 + lr) * 64 + kk * 32 + lh * 8];
#pragma unroll
            for (int mi = 0; mi < 4; ++mi)
#pragma unroll
                for (int ni = 0; ni < 4; ++ni)
                    acc[mi][ni] = __builtin_amdgcn_mfma_f32_16x16x32_bf16(
                        af[mi], bfr[ni], acc[mi][ni], 0, 0, 0);
        }
        __syncthreads();  // next buf staged + everyone done reading cur
        cur ^= 1;
    }

    // epilogue: C/D layout col = lane&15, row = (lane>>4)*4 + r
    const int colg = lane & 15;
    const int row4 = (lane >> 4) * 4;
#pragma unroll
    for (int ni = 0; ni < 4; ++ni) {
        const int n = n0 + wv * 64 + ni * 16 + colg;
        const float bv = bias[cid * HID + n];
#pragma unroll
        for (int mi = 0; mi < 4; ++mi) {
#pragma unroll
            for (int r = 0; r < 4; ++r) {
                const int ml = mi * 16 + row4 + r;  // token index within batch = PE index
                const size_t gi = ((size_t)batch * HSEQ + ml) * HID + n;
                float v = acc[mi][ni][r] + bv;
                if constexpr (EPI == 0) {
                    v = fmaxf(v, 0.f) + pe[ml * HID + n];
                    hout[gi] = (__bf16)v;
                } else if constexpr (EPI == 1) {
                    v = fmaxf(v, 0.f);
                    hout[gi] = (__bf16)v;
                } else {
                    fout[gi] = v;
                }
            }
        }
    }
}

// ---------------- launcher ----------------

extern "C" void kernel_launch(void* const* d_in, const int* in_sizes, int n_in,
                              void* d_out, int out_size, void* d_ws, size_t ws_size,
                              hipStream_t stream) {
    (void)in_sizes; (void)n_in; (void)out_size; (void)ws_size;
    const float* x   = (const float*)d_in[0];
    const int*   cat = (const int*)d_in[1];
    const float* W1  = (const float*)d_in[2];
    const float* b1  = (const float*)d_in[3];
    const float* W2  = (const float*)d_in[4];
    const float* b2  = (const float*)d_in[5];
    const float* W3  = (const float*)d_in[6];
    const float* b3  = (const float*)d_in[7];
    float* out = (float*)d_out;

    // Workspace layout (~67.3 MB needed):
    char* ws = (char*)d_ws;
    __bf16* h2  = (__bf16*)(ws);                        // 33,554,432 B
    __bf16* xb  = (__bf16*)(ws + 33554432);             //  2,097,152 B
    __bf16* W1t = (__bf16*)(ws + 35651584);             //  1,048,576 B
    __bf16* W2t = (__bf16*)(ws + 36700160);             // 16,777,216 B
    __bf16* W3t = (__bf16*)(ws + 53477376);             // 16,777,216 B
    float*  pe  = (float*) (ws + 70254592);             //    262,144 B
    // h1 (bf16, 32 MB) lives in the first half of d_out (f32 64 MB);
    // it is fully consumed by layer 2 before layer 3 overwrites d_out.
    __bf16* h1 = (__bf16*)d_out;

    pe_kernel<<<dim3(HSEQ), dim3(512), 0, stream>>>(pe);
    cvt_x_kernel<<<dim3(NTOK * DIN / 4 / 256), dim3(256), 0, stream>>>(x, xb);
    transpose_kernel<<<dim3(16, 1, NCAT),  dim3(256), 0, stream>>>(W1, W1t, DIN, HID);
    transpose_kernel<<<dim3(16, 16, NCAT), dim3(256), 0, stream>>>(W2, W2t, HID, HID);
    transpose_kernel<<<dim3(16, 16, NCAT), dim3(256), 0, stream>>>(W3, W3t, HID, HID);

    gemm_cat<DIN, 0><<<dim3(4, NBATCH), dim3(256), 0, stream>>>(xb, W1t, b1, pe, cat, h1, nullptr);
    gemm_cat<HID, 1><<<dim3(4, NBATCH), dim3(256), 0, stream>>>(h1, W2t, b2, nullptr, cat, h2, nullptr);
    gemm_cat<HID, 2><<<dim3(4, NBATCH), dim3(256), 0, stream>>>(h2, W3t, b3, nullptr, cat, nullptr, out);
}